// Round 2
// baseline (1661.033 us; speedup 1.0000x reference)
//
#include <hip/hip_runtime.h>
#include <hip/hip_bf16.h>

// ---------------------------------------------------------------------------
// EncoderLayer with GroupAttention — fp32 correctness-first baseline (r2).
//
// r2 fix: eos_mask arrives as int32 (harness converts bool -> int), not bytes.
//         Round-1 failure signature (gp absmax 0.2518 ~= ref gp[0][1]) matched
//         the byte-misread exactly.
//
// Key algebraic reductions:
//  * group-attention scores are tridiagonal => only adjacent dot products
//  * t = M@tri, g = exp(tri@t) collapse to prefix sums of c[i]=log(na_adj+1e-9)
//  * na / group_prob outputs are O(1)-per-element fills from prefix tables
// ---------------------------------------------------------------------------

#define BS   4
#define S    512
#define DM   1024
#define H    16
#define DK   64
#define FF   4096

static constexpr size_t XSZ  = (size_t)BS * S * DM;      // 2,097,152
static constexpr size_t ATTSZ = (size_t)BS * H * S * S;  // 16,777,216

// workspace layout (floats), with aliasing across pipeline phases
static constexpr size_t WS_CTX  = 0;                  // LN(gn) of x      [XSZ]
static constexpr size_t WS_XN   = XSZ;                // LN(ln1) of x     [XSZ]
static constexpr size_t WS_QG   = 2 * XSZ;            // group q          [XSZ]
static constexpr size_t WS_KG   = 3 * XSZ;            // group k          [XSZ]
static constexpr size_t WS_NAP  = 4 * XSZ;            // na_adj per bh    [64*512]
static constexpr size_t WS_P    = WS_NAP + 64 * 512;  // prefix sums      [64*512]
static constexpr size_t WS_ATT  = WS_P + 64 * 512;    // att matrix       [ATTSZ]
static constexpr size_t WS_Q2   = WS_CTX;             // alias (ctx dead)
static constexpr size_t WS_K2   = WS_QG;              // alias (qg dead)
static constexpr size_t WS_V2   = WS_KG;              // alias (kg dead)
static constexpr size_t WS_XMID = WS_XN;              // alias (xn dead)
static constexpr size_t WS_XN2  = WS_ATT + ATTSZ;     // LN2 out          [XSZ]
static constexpr size_t WS_H1   = WS_ATT;             // alias (att dead) [BS*S*FF]

// ---------------------------------------------------------------------------
// LN kernels: one block per row (1024 floats), 256 threads, float4 loads.
// ---------------------------------------------------------------------------
__global__ __launch_bounds__(256) void ln_dual_kernel(
    const float* __restrict__ x,
    const float* __restrict__ g1, const float* __restrict__ b1,
    const float* __restrict__ g2, const float* __restrict__ b2,
    float* __restrict__ o1, float* __restrict__ o2)
{
    __shared__ float sred[8];
    int row = blockIdx.x, tid = threadIdx.x;
    const float4 v = ((const float4*)(x + (size_t)row * DM))[tid];
    float s = v.x + v.y + v.z + v.w;
    float q = v.x * v.x + v.y * v.y + v.z * v.z + v.w * v.w;
#pragma unroll
    for (int o = 32; o > 0; o >>= 1) { s += __shfl_down(s, o); q += __shfl_down(q, o); }
    if ((tid & 63) == 0) { sred[(tid >> 6) * 2] = s; sred[(tid >> 6) * 2 + 1] = q; }
    __syncthreads();
    s = sred[0] + sred[2] + sred[4] + sred[6];
    q = sred[1] + sred[3] + sred[5] + sred[7];
    float mean = s * (1.f / DM);
    float var  = q * (1.f / DM) - mean * mean;
    float rstd = rsqrtf(var + 1e-5f);
    float4 G1 = ((const float4*)g1)[tid], B1 = ((const float4*)b1)[tid];
    float4 G2 = ((const float4*)g2)[tid], B2 = ((const float4*)b2)[tid];
    float4 r1, r2;
    float n0 = (v.x - mean) * rstd, n1 = (v.y - mean) * rstd;
    float n2 = (v.z - mean) * rstd, n3 = (v.w - mean) * rstd;
    r1.x = n0 * G1.x + B1.x; r1.y = n1 * G1.y + B1.y; r1.z = n2 * G1.z + B1.z; r1.w = n3 * G1.w + B1.w;
    r2.x = n0 * G2.x + B2.x; r2.y = n1 * G2.y + B2.y; r2.z = n2 * G2.z + B2.z; r2.w = n3 * G2.w + B2.w;
    ((float4*)(o1 + (size_t)row * DM))[tid] = r1;
    ((float4*)(o2 + (size_t)row * DM))[tid] = r2;
}

__global__ __launch_bounds__(256) void ln_single_kernel(
    const float* __restrict__ x,
    const float* __restrict__ g1, const float* __restrict__ b1,
    float* __restrict__ o1)
{
    __shared__ float sred[8];
    int row = blockIdx.x, tid = threadIdx.x;
    const float4 v = ((const float4*)(x + (size_t)row * DM))[tid];
    float s = v.x + v.y + v.z + v.w;
    float q = v.x * v.x + v.y * v.y + v.z * v.z + v.w * v.w;
#pragma unroll
    for (int o = 32; o > 0; o >>= 1) { s += __shfl_down(s, o); q += __shfl_down(q, o); }
    if ((tid & 63) == 0) { sred[(tid >> 6) * 2] = s; sred[(tid >> 6) * 2 + 1] = q; }
    __syncthreads();
    s = sred[0] + sred[2] + sred[4] + sred[6];
    q = sred[1] + sred[3] + sred[5] + sred[7];
    float mean = s * (1.f / DM);
    float var  = q * (1.f / DM) - mean * mean;
    float rstd = rsqrtf(var + 1e-5f);
    float4 G1 = ((const float4*)g1)[tid], B1 = ((const float4*)b1)[tid];
    float4 r1;
    r1.x = (v.x - mean) * rstd * G1.x + B1.x;
    r1.y = (v.y - mean) * rstd * G1.y + B1.y;
    r1.z = (v.z - mean) * rstd * G1.z + B1.z;
    r1.w = (v.w - mean) * rstd * G1.w + B1.w;
    ((float4*)(o1 + (size_t)row * DM))[tid] = r1;
}

// ---------------------------------------------------------------------------
// Group q/k projection: per (b,h), q = ctx_head @ wq + bq (64x64 weights).
// Block = 512 threads handles 8 rows; weights staged in LDS.
// ---------------------------------------------------------------------------
__global__ __launch_bounds__(512) void groupqk_kernel(
    const float* __restrict__ ctx,
    const float* __restrict__ wq, const float* __restrict__ bq,
    const float* __restrict__ wk, const float* __restrict__ bk,
    float* __restrict__ qg, float* __restrict__ kg)
{
    __shared__ float Wq[64][65], Wk[64][65], Ct[8][65];
    int tid = threadIdx.x;
    for (int t = tid; t < 4096; t += 512) {
        Wq[t >> 6][t & 63] = wq[t];
        Wk[t >> 6][t & 63] = wk[t];
    }
    int blk = blockIdx.x;
    int bh = blk >> 6;            // 64 row-blocks per bh
    int i0 = (blk & 63) * 8;
    int b = bh >> 4, h = bh & 15;
    {
        int r = tid >> 6, c = tid & 63;
        Ct[r][c] = ctx[((size_t)b * S + i0 + r) * DM + h * 64 + c];
    }
    __syncthreads();
    int r = tid >> 6, j = tid & 63;
    float aq = bq[j], ak = bk[j];
#pragma unroll
    for (int d = 0; d < 64; ++d) {
        float c = Ct[r][d];
        aq = fmaf(c, Wq[d][j], aq);
        ak = fmaf(c, Wk[d][j], ak);
    }
    size_t o = ((size_t)bh * S + i0 + r) * DK + j;
    qg[o] = aq;
    kg[o] = ak;
}

// ---------------------------------------------------------------------------
// Adjacent scores -> masked 2-entry softmax -> symmetric na_adj -> prefix sums.
// One block (256 threads) per (b,h).  eos_mask is int32 (harness bool->int).
// ---------------------------------------------------------------------------
__global__ __launch_bounds__(256) void adj_kernel(
    const float* __restrict__ qg, const float* __restrict__ kg,
    const int* __restrict__ eos, const float* __restrict__ prior,
    float* __restrict__ nap, float* __restrict__ Pout)
{
    __shared__ float su[S], sl[S], nu[S], nl[S], cl[S];
    int tid = threadIdx.x, bh = blockIdx.x, b = bh >> 4;
    const float* qb = qg + (size_t)bh * S * DK;
    const float* kb = kg + (size_t)bh * S * DK;
    for (int i = tid; i < S; i += 256) {
        float du = 0.f, dl = 0.f;
        const float* qi = qb + (size_t)i * DK;
        if (i < S - 1) {
            const float* kn = kb + (size_t)(i + 1) * DK;
            for (int d = 0; d < DK; ++d) du = fmaf(qi[d], kn[d], du);
        }
        if (i > 0) {
            const float* kp = kb + (size_t)(i - 1) * DK;
            for (int d = 0; d < DK; ++d) dl = fmaf(qi[d], kp[d], dl);
        }
        su[i] = du * (1.f / DK);
        sl[i] = dl * (1.f / DK);
    }
    __syncthreads();
    for (int i = tid; i < S; i += 256) {
        bool vu = (i < S - 1) && (eos[(size_t)b * S * S + (size_t)i * S + (i + 1)] != 0);
        bool vl = (i > 0)     && (eos[(size_t)b * S * S + (size_t)i * S + (i - 1)] != 0);
        float eu = 0.f, el = 0.f;
        if (vu && vl) {
            float m = fmaxf(su[i], sl[i]);
            eu = expf(su[i] - m);
            el = expf(sl[i] - m);
        } else if (vu) eu = 1.f;
        else if (vl) el = 1.f;
        float Z = eu + el;
        if (Z == 0.f) Z = 1.f;
        nu[i] = eu / Z;
        nl[i] = el / Z;
    }
    __syncthreads();
    float pr = prior[0];
    for (int i = tid; i < S - 1; i += 256) {
        float v = sqrtf(nu[i] * nl[i + 1] + 1e-4f);
        v = pr + (1.f - pr) * v;
        nap[(size_t)bh * S + i] = v;
        cl[i] = logf(v + 1e-9f);
    }
    if (tid == 0) cl[S - 1] = 0.f;
    __syncthreads();
    // wave-0 inclusive scan over 64 segments of 8 -> exact prefix table P[0..511]
    if (tid < 64) {
        float loc[8];
        float s8 = 0.f;
#pragma unroll
        for (int e = 0; e < 8; ++e) { loc[e] = cl[tid * 8 + e]; s8 += loc[e]; }
        float v = s8;
#pragma unroll
        for (int o = 1; o < 64; o <<= 1) {
            float n = __shfl_up(v, o);
            if (tid >= o) v += n;
        }
        float run = v - s8;   // exclusive prefix of this segment
        float* Pb = Pout + (size_t)bh * S;
#pragma unroll
        for (int e = 0; e < 8; ++e) { Pb[tid * 8 + e] = run; run += loc[e]; }
    }
}

// ---------------------------------------------------------------------------
// na output fill: baseline everywhere, adjacent pairs get na_adj. 64 MB write.
// ---------------------------------------------------------------------------
__global__ void na_fill_kernel(const float* __restrict__ nap,
                               const float* __restrict__ prior,
                               float* __restrict__ out_na)
{
    float pr = prior[0];
    float base = pr + (1.f - pr) * 0.01f;
    size_t n4 = ATTSZ / 4;
    for (size_t t = (size_t)blockIdx.x * 256 + threadIdx.x; t < n4;
         t += (size_t)gridDim.x * 256) {
        size_t e = t * 4;
        int bh = (int)(e >> 18);
        int rem = (int)(e & 262143);
        int i = rem >> 9;
        int j0 = rem & 511;
        float4 v;
        float* vp = &v.x;
#pragma unroll
        for (int jj = 0; jj < 4; ++jj) {
            int j = j0 + jj;
            float val = base;
            if (j == i + 1)      val = nap[(size_t)bh * S + i];
            else if (j + 1 == i) val = nap[(size_t)bh * S + j];
            vp[jj] = val;
        }
        ((float4*)out_na)[t] = v;
    }
}

// ---------------------------------------------------------------------------
// group_prob fill via prefix-sum closed form. 64 MB write + 16.7M expf.
// grid = (S/4 row-groups, BS*H); block handles 4 rows.
// ---------------------------------------------------------------------------
__global__ __launch_bounds__(256) void gp_fill_kernel(
    const float* __restrict__ Pin, const float* __restrict__ prior,
    float* __restrict__ out_gp)
{
    __shared__ float Pl[S];
    int bh = blockIdx.y;
    int i0 = blockIdx.x * 4;
    int tid = threadIdx.x;
    Pl[tid]       = Pin[(size_t)bh * S + tid];
    Pl[tid + 256] = Pin[(size_t)bh * S + tid + 256];
    __syncthreads();
    float pr = prior[0];
    float base = pr + (1.f - pr) * 0.01f;
    int r  = tid >> 6;
    int j0 = (tid & 63) * 8;
    int i  = i0 + r;
    float vals[8];
#pragma unroll
    for (int jj = 0; jj < 8; ++jj) {
        int j = j0 + jj;
        float val;
        if (i == j) {
            val = base;
        } else {
            int a = min(i, j), bb = max(i, j);
            float t1 = Pl[min(bb, S - 2) + 1] - Pl[max(a - 1, 0)];
            float t2 = Pl[min(bb - 1, S - 2) + 1] - Pl[a];
            val = expf(t1 + t2) + 1e-4f;
        }
        vals[jj] = val;
    }
    float* orow = out_gp + ((size_t)bh * S + i) * S + j0;
    *(float4*)&orow[0] = *(float4*)&vals[0];
    *(float4*)&orow[4] = *(float4*)&vals[4];
}

// ---------------------------------------------------------------------------
// Generic fp32 tiled GEMM: C(MxN) = A(MxK) @ B(KxN) + bias (+relu|+resid).
// BM=64, BN=128, BK=8; 256 threads; 4x8 micro-tile per thread.
// HEAD: write output in (b, h, s, d) head layout (for attention q2/k2/v2).
// ---------------------------------------------------------------------------
template <int EPI, bool HEAD>   // EPI: 0=bias, 1=bias+relu, 2=bias+resid
__global__ __launch_bounds__(256) void gemm_kernel(
    const float* __restrict__ A, const float* __restrict__ B,
    const float* __restrict__ bias, const float* __restrict__ resid,
    float* __restrict__ out, int M, int N, int K)
{
    __shared__ float Ast[8][68];    // transposed A tile [k][m]
    __shared__ float Bs[8][132];
    int tid = threadIdx.x;
    int m0 = blockIdx.y * 64, n0 = blockIdx.x * 128;
    int ty = tid >> 4, tx = tid & 15;
    float acc[4][8] = {};
    for (int k0 = 0; k0 < K; k0 += 8) {
        {
            int r = tid >> 2, c = (tid & 3) * 2;
            float2 v = *(const float2*)&A[(size_t)(m0 + r) * K + k0 + c];
            Ast[c][r] = v.x;
            Ast[c + 1][r] = v.y;
        }
        {
            int r = tid >> 5, c = (tid & 31) * 4;
            *(float4*)&Bs[r][c] = *(const float4*)&B[(size_t)(k0 + r) * N + n0 + c];
        }
        __syncthreads();
#pragma unroll
        for (int k = 0; k < 8; ++k) {
            float a[4], bb[8];
            *(float4*)a        = *(const float4*)&Ast[k][ty * 4];
            *(float4*)&bb[0]   = *(const float4*)&Bs[k][tx * 8];
            *(float4*)&bb[4]   = *(const float4*)&Bs[k][tx * 8 + 4];
#pragma unroll
            for (int i = 0; i < 4; ++i)
#pragma unroll
                for (int j = 0; j < 8; ++j)
                    acc[i][j] = fmaf(a[i], bb[j], acc[i][j]);
        }
        __syncthreads();
    }
#pragma unroll
    for (int i = 0; i < 4; ++i) {
        int m = m0 + ty * 4 + i;
#pragma unroll
        for (int j = 0; j < 8; ++j) {
            int n = n0 + tx * 8 + j;
            float v = acc[i][j] + bias[n];
            if constexpr (EPI == 1) v = fmaxf(v, 0.f);
            if constexpr (EPI == 2) v += resid[(size_t)m * N + n];
            if constexpr (HEAD) {
                int b = m >> 9, si = m & 511, h = n >> 6, d = n & 63;
                out[(((size_t)(b * H + h)) * S + si) * DK + d] = v;
            } else {
                out[(size_t)m * N + n] = v;
            }
        }
    }
}

// ---------------------------------------------------------------------------
// Attention scores: att[bh][i][j] = dot64(q2[bh][i], k2[bh][j]) / 8.
// A@B^T with on-the-fly transpose of the K tile into LDS.
// ---------------------------------------------------------------------------
__global__ __launch_bounds__(256) void scores_kernel(
    const float* __restrict__ q2, const float* __restrict__ k2,
    float* __restrict__ att)
{
    __shared__ float Ast[8][68];
    __shared__ float Bs[8][132];
    int tid = threadIdx.x;
    int bh = blockIdx.z;
    const float* A  = q2 + (size_t)bh * S * DK;
    const float* Bk = k2 + (size_t)bh * S * DK;
    float* C = att + (size_t)bh * S * S;
    int m0 = blockIdx.y * 64;
    int n0 = blockIdx.x * 128;
    int ty = tid >> 4, tx = tid & 15;
    float acc[4][8] = {};
    for (int k0 = 0; k0 < DK; k0 += 8) {
        {
            int r = tid >> 2, c = (tid & 3) * 2;
            float2 v = *(const float2*)&A[(size_t)(m0 + r) * DK + k0 + c];
            Ast[c][r] = v.x;
            Ast[c + 1][r] = v.y;
        }
        {
            int jl = tid >> 1, cc = (tid & 1) * 4;
            float4 v = *(const float4*)&Bk[(size_t)(n0 + jl) * DK + k0 + cc];
            Bs[cc][jl] = v.x; Bs[cc + 1][jl] = v.y;
            Bs[cc + 2][jl] = v.z; Bs[cc + 3][jl] = v.w;
        }
        __syncthreads();
#pragma unroll
        for (int k = 0; k < 8; ++k) {
            float a[4], bb[8];
            *(float4*)a      = *(const float4*)&Ast[k][ty * 4];
            *(float4*)&bb[0] = *(const float4*)&Bs[k][tx * 8];
            *(float4*)&bb[4] = *(const float4*)&Bs[k][tx * 8 + 4];
#pragma unroll
            for (int i = 0; i < 4; ++i)
#pragma unroll
                for (int j = 0; j < 8; ++j)
                    acc[i][j] = fmaf(a[i], bb[j], acc[i][j]);
        }
        __syncthreads();
    }
#pragma unroll
    for (int i = 0; i < 4; ++i)
#pragma unroll
        for (int j = 0; j < 8; ++j)
            C[(size_t)(m0 + ty * 4 + i) * S + n0 + tx * 8 + j] = acc[i][j] * 0.125f;
}

// ---------------------------------------------------------------------------
// Row softmax x group_prob, in place on att. One block per (bh, row).
// ---------------------------------------------------------------------------
__global__ __launch_bounds__(256) void softmax_gp_kernel(
    float* __restrict__ att, const float* __restrict__ gp)
{
    __shared__ float sred[4];
    size_t row = blockIdx.x;
    float* ar = att + row * S;
    const float* gr = gp + row * S;
    int tid = threadIdx.x;
    float2 v = ((const float2*)ar)[tid];
    float m = fmaxf(v.x, v.y);
#pragma unroll
    for (int o = 32; o > 0; o >>= 1) m = fmaxf(m, __shfl_down(m, o));
    if ((tid & 63) == 0) sred[tid >> 6] = m;
    __syncthreads();
    m = fmaxf(fmaxf(sred[0], sred[1]), fmaxf(sred[2], sred[3]));
    float e0 = expf(v.x - m), e1 = expf(v.y - m);
    float s = e0 + e1;
#pragma unroll
    for (int o = 32; o > 0; o >>= 1) s += __shfl_down(s, o);
    __syncthreads();
    if ((tid & 63) == 0) sred[tid >> 6] = s;
    __syncthreads();
    s = sred[0] + sred[1] + sred[2] + sred[3];
    float inv = 1.f / s;
    float2 g = ((const float2*)gr)[tid];
    float2 o2;
    o2.x = e0 * inv * g.x;
    o2.y = e1 * inv * g.y;
    ((float2*)ar)[tid] = o2;
}

// ---------------------------------------------------------------------------
// PV: sa = att @ v2, fused residual: xmid[b,i,h*64+d] = x[...] + sa.
// BM=64 rows, N=64 (full), BK=16. One block per (bh, row-block).
// ---------------------------------------------------------------------------
__global__ __launch_bounds__(256) void pv_kernel(
    const float* __restrict__ att, const float* __restrict__ v2,
    const float* __restrict__ x, float* __restrict__ xmid)
{
    __shared__ float Ast[16][68];
    __shared__ float Bs[16][68];
    int tid = threadIdx.x;
    int bh = blockIdx.z, b = bh >> 4, h = bh & 15;
    const float* A = att + (size_t)bh * S * S;
    const float* V = v2 + (size_t)bh * S * DK;
    int m0 = blockIdx.y * 64;
    int ty = tid >> 4, tx = tid & 15;
    float acc[4][4] = {};
    for (int k0 = 0; k0 < S; k0 += 16) {
        {
            int r = tid >> 2, c = (tid & 3) * 4;
            float4 v = *(const float4*)&A[(size_t)(m0 + r) * S + k0 + c];
            Ast[c][r] = v.x; Ast[c + 1][r] = v.y;
            Ast[c + 2][r] = v.z; Ast[c + 3][r] = v.w;
        }
        {
            int r = tid >> 4, c = (tid & 15) * 4;
            *(float4*)&Bs[r][c] = *(const float4*)&V[(size_t)(k0 + r) * DK + c];
        }
        __syncthreads();
#pragma unroll
        for (int k = 0; k < 16; ++k) {
            float a[4], bb[4];
            *(float4*)a  = *(const float4*)&Ast[k][ty * 4];
            *(float4*)bb = *(const float4*)&Bs[k][tx * 4];
#pragma unroll
            for (int i = 0; i < 4; ++i)
#pragma unroll
                for (int j = 0; j < 4; ++j)
                    acc[i][j] = fmaf(a[i], bb[j], acc[i][j]);
        }
        __syncthreads();
    }
#pragma unroll
    for (int i = 0; i < 4; ++i) {
        int si = m0 + ty * 4 + i;
#pragma unroll
        for (int j = 0; j < 4; ++j) {
            int d = tx * 4 + j;
            size_t o = ((size_t)b * S + si) * DM + h * 64 + d;
            xmid[o] = x[o] + acc[i][j];
        }
    }
}

// ---------------------------------------------------------------------------
extern "C" void kernel_launch(void* const* d_in, const int* in_sizes, int n_in,
                              void* d_out, int out_size, void* d_ws, size_t ws_size,
                              hipStream_t stream)
{
    const float* x     = (const float*)d_in[0];
    const int* eos     = (const int*)d_in[1];   // harness converts bool -> int32
    const float* prior = (const float*)d_in[2];
    const float* gn_g  = (const float*)d_in[3];
    const float* gn_b  = (const float*)d_in[4];
    const float* wq    = (const float*)d_in[5];
    const float* bq    = (const float*)d_in[6];
    const float* wk    = (const float*)d_in[7];
    const float* bk    = (const float*)d_in[8];
    const float* fq_w  = (const float*)d_in[9];
    const float* fq_b  = (const float*)d_in[10];
    const float* fk_w  = (const float*)d_in[11];
    const float* fk_b  = (const float*)d_in[12];
    const float* fv_w  = (const float*)d_in[13];
    const float* fv_b  = (const float*)d_in[14];
    const float* ln1_g = (const float*)d_in[15];
    const float* ln1_b = (const float*)d_in[16];
    const float* ff_w1 = (const float*)d_in[17];
    const float* ff_b1 = (const float*)d_in[18];
    const float* ff_w2 = (const float*)d_in[19];
    const float* ff_b2 = (const float*)d_in[20];
    const float* ln2_g = (const float*)d_in[21];
    const float* ln2_b = (const float*)d_in[22];

    float* ws = (float*)d_ws;
    float* out_x  = (float*)d_out;
    float* out_gp = out_x + XSZ;
    float* out_na = out_gp + ATTSZ;

    const int NTOK = BS * S;  // 2048

    // 1. both pre-norms of x in one pass
    ln_dual_kernel<<<NTOK, 256, 0, stream>>>(x, gn_g, gn_b, ln1_g, ln1_b,
                                             ws + WS_CTX, ws + WS_XN);
    // 2. group q/k projection (per-head 64x64)
    groupqk_kernel<<<BS * H * (S / 8), 512, 0, stream>>>(
        ws + WS_CTX, wq, bq, wk, bk, ws + WS_QG, ws + WS_KG);
    // 3. adjacent scores -> na_adj -> prefix sums
    adj_kernel<<<BS * H, 256, 0, stream>>>(ws + WS_QG, ws + WS_KG, eos, prior,
                                           ws + WS_NAP, ws + WS_P);
    // 4. na output fill
    na_fill_kernel<<<2048, 256, 0, stream>>>(ws + WS_NAP, prior, out_na);
    // 5. group_prob output fill
    gp_fill_kernel<<<dim3(S / 4, BS * H), 256, 0, stream>>>(ws + WS_P, prior, out_gp);
    // 6. q2/k2/v2 projections (head layout)
    gemm_kernel<0, true><<<dim3(DM / 128, NTOK / 64), 256, 0, stream>>>(
        ws + WS_XN, fq_w, fq_b, nullptr, ws + WS_Q2, NTOK, DM, DM);
    gemm_kernel<0, true><<<dim3(DM / 128, NTOK / 64), 256, 0, stream>>>(
        ws + WS_XN, fk_w, fk_b, nullptr, ws + WS_K2, NTOK, DM, DM);
    gemm_kernel<0, true><<<dim3(DM / 128, NTOK / 64), 256, 0, stream>>>(
        ws + WS_XN, fv_w, fv_b, nullptr, ws + WS_V2, NTOK, DM, DM);
    // 7. attention scores
    scores_kernel<<<dim3(S / 128, S / 64, BS * H), 256, 0, stream>>>(
        ws + WS_Q2, ws + WS_K2, ws + WS_ATT);
    // 8. softmax * group_prob (in place)
    softmax_gp_kernel<<<BS * H * S, 256, 0, stream>>>(ws + WS_ATT, out_gp);
    // 9. PV + residual -> xmid
    pv_kernel<<<dim3(1, S / 64, BS * H), 256, 0, stream>>>(
        ws + WS_ATT, ws + WS_V2, x, ws + WS_XMID);
    // 10. LN2
    ln_single_kernel<<<NTOK, 256, 0, stream>>>(ws + WS_XMID, ln2_g, ln2_b, ws + WS_XN2);
    // 11. FFN1 (relu)
    gemm_kernel<1, false><<<dim3(FF / 128, NTOK / 64), 256, 0, stream>>>(
        ws + WS_XN2, ff_w1, ff_b1, nullptr, ws + WS_H1, NTOK, FF, DM);
    // 12. FFN2 + residual -> final x output
    gemm_kernel<2, false><<<dim3(DM / 128, NTOK / 64), 256, 0, stream>>>(
        ws + WS_H1, ff_w2, ff_b2, ws + WS_XMID, out_x, NTOK, DM, FF);
}

// Round 4
// 470.485 us; speedup vs baseline: 3.5305x; 3.5305x over previous
//
#include <hip/hip_runtime.h>
#include <hip/hip_bf16.h>

// ---------------------------------------------------------------------------
// EncoderLayer with GroupAttention — r4: bf16 MFMA for all large GEMMs.
// (r3 resubmit + __align__(16) on LDS tiles; r3 never ran: GPU acq timeout)
//
//  * group path (gp/na outputs) stays fp32 (validated in r2)
//  * GEMMs: fused QKV (N=3072), FFN1, FFN2, scores, PV -> mfma_f32_16x16x32_bf16
//  * all GEMMs in BT form: A [M][K], B^T [N][K], both k-contiguous
//  * weights transposed+converted to bf16 once per call
//  * staging via __builtin_amdgcn_global_load_lds width=16 (m97 structure)
// ---------------------------------------------------------------------------

#define BS   4
#define S    512
#define DM   1024
#define H    16
#define DK   64
#define FF   4096

typedef unsigned short u16;
typedef __attribute__((ext_vector_type(8))) short bf16x8;
typedef __attribute__((ext_vector_type(4))) float f32x4;

static constexpr size_t XSZ   = (size_t)BS * S * DM;      // 2,097,152
static constexpr size_t ATTSZ = (size_t)BS * H * S * S;   // 16,777,216

__device__ __forceinline__ u16 f2bf(float f) {
    union { float f; unsigned u; } v; v.f = f;
    unsigned u = v.u;
    return (u16)((u + 0x7FFFu + ((u >> 16) & 1u)) >> 16);
}
__device__ __forceinline__ float bf2f(u16 h) {
    union { unsigned u; float f; } v; v.u = ((unsigned)h) << 16;
    return v.f;
}

__device__ __forceinline__ void gload16(const void* g, void* lds) {
    __builtin_amdgcn_global_load_lds(
        (const __attribute__((address_space(1))) unsigned int*)g,
        (__attribute__((address_space(3))) unsigned int*)lds,
        16, 0, 0);
}

// ---------------------------------------------------------------------------
// MFMA GEMM core: block = 128 x (2*NF*16), 256 threads = 4 waves (2x2),
// wave tile 64 x (NF*16), BK=32. A [M][K] bf16, B^T [N][K] bf16.
// Single-buffered LDS, global_load_lds width 16 (m97 structure).
// ---------------------------------------------------------------------------
template <int NF>
__device__ __forceinline__ void mfma_loop(
    const u16* __restrict__ Ag,   // block A base: A + m0*lda
    const u16* __restrict__ Bg,   // block B base: BT + n0*ldb
    int lda, int ldb, int K,
    u16* As, u16* Bs,             // LDS: As[128*32], Bs[2*NF*16*32]
    f32x4 (&acc)[4][NF])
{
    const int tid  = threadIdx.x;
    const int lane = tid & 63;
    const int wv   = tid >> 6;
    const int wr   = wv >> 1, wc = wv & 1;
    const int arow = lane & 15;
    const int ak   = (lane >> 4) * 8;
    constexpr int BROWS = 2 * NF * 16;      // 128 or 64
    constexpr int BISS  = BROWS / 64;       // B staging issues (2 or 1)

    for (int k0 = 0; k0 < K; k0 += 32) {
        // stage A tile [128][32]
#pragma unroll
        for (int i = 0; i < 2; ++i) {
            int chunk = i * 256 + tid;
            int r = chunk >> 2, c = chunk & 3;
            gload16(Ag + (size_t)r * lda + k0 + c * 8,
                    &As[(i * 256 + wv * 64) * 8]);
        }
        // stage B tile [BROWS][32]
#pragma unroll
        for (int i = 0; i < BISS; ++i) {
            int chunk = i * 256 + tid;
            int r = chunk >> 2, c = chunk & 3;
            gload16(Bg + (size_t)r * ldb + k0 + c * 8,
                    &Bs[(i * 256 + wv * 64) * 8]);
        }
        __syncthreads();
        bf16x8 af[4], bfr[NF];
#pragma unroll
        for (int mi = 0; mi < 4; ++mi)
            af[mi] = *(const bf16x8*)&As[(wr * 64 + mi * 16 + arow) * 32 + ak];
#pragma unroll
        for (int nj = 0; nj < NF; ++nj)
            bfr[nj] = *(const bf16x8*)&Bs[(wc * NF * 16 + nj * 16 + arow) * 32 + ak];
#pragma unroll
        for (int mi = 0; mi < 4; ++mi)
#pragma unroll
            for (int nj = 0; nj < NF; ++nj)
                acc[mi][nj] = __builtin_amdgcn_mfma_f32_16x16x32_bf16(
                    af[mi], bfr[nj], acc[mi][nj], 0, 0, 0);
        __syncthreads();
    }
}

// ---------------------------------------------------------------------------
// Weight transpose + fp32->bf16:  src [K][N] fp32  ->  dst [N][K] bf16.
// ---------------------------------------------------------------------------
__global__ __launch_bounds__(256) void transcvt(
    const float* __restrict__ src, u16* __restrict__ dst, int K, int N)
{
    __shared__ __align__(16) u16 T[64][80];
    int k0 = blockIdx.x * 64, n0 = blockIdx.y * 64, tid = threadIdx.x;
    int r = tid >> 2, c0 = (tid & 3) * 16;
#pragma unroll
    for (int i = 0; i < 4; ++i) {
        float4 v = *(const float4*)&src[(size_t)(k0 + r) * N + n0 + c0 + i * 4];
        T[c0 + i * 4 + 0][r] = f2bf(v.x);
        T[c0 + i * 4 + 1][r] = f2bf(v.y);
        T[c0 + i * 4 + 2][r] = f2bf(v.z);
        T[c0 + i * 4 + 3][r] = f2bf(v.w);
    }
    __syncthreads();
    int n = tid >> 2, kc = (tid & 3) * 16;
#pragma unroll
    for (int i = 0; i < 2; ++i) {
        ushort4 a = *(const ushort4*)&T[n][kc + i * 8];
        ushort4 b = *(const ushort4*)&T[n][kc + i * 8 + 4];
        *(ushort4*)&dst[(size_t)(n0 + n) * K + k0 + kc + i * 8]     = a;
        *(ushort4*)&dst[(size_t)(n0 + n) * K + k0 + kc + i * 8 + 4] = b;
    }
}

// ---------------------------------------------------------------------------
// LN kernels. ln_dual: ctx fp32 (group path) + xn bf16 (QKV GEMM A-operand).
// ---------------------------------------------------------------------------
__global__ __launch_bounds__(256) void ln_dual_kernel(
    const float* __restrict__ x,
    const float* __restrict__ g1, const float* __restrict__ b1,
    const float* __restrict__ g2, const float* __restrict__ b2,
    float* __restrict__ o1, u16* __restrict__ o2)
{
    __shared__ float sred[8];
    int row = blockIdx.x, tid = threadIdx.x;
    const float4 v = ((const float4*)(x + (size_t)row * DM))[tid];
    float s = v.x + v.y + v.z + v.w;
    float q = v.x * v.x + v.y * v.y + v.z * v.z + v.w * v.w;
#pragma unroll
    for (int o = 32; o > 0; o >>= 1) { s += __shfl_down(s, o); q += __shfl_down(q, o); }
    if ((tid & 63) == 0) { sred[(tid >> 6) * 2] = s; sred[(tid >> 6) * 2 + 1] = q; }
    __syncthreads();
    s = sred[0] + sred[2] + sred[4] + sred[6];
    q = sred[1] + sred[3] + sred[5] + sred[7];
    float mean = s * (1.f / DM);
    float var  = q * (1.f / DM) - mean * mean;
    float rstd = rsqrtf(var + 1e-5f);
    float4 G1 = ((const float4*)g1)[tid], B1 = ((const float4*)b1)[tid];
    float4 G2 = ((const float4*)g2)[tid], B2 = ((const float4*)b2)[tid];
    float n0 = (v.x - mean) * rstd, n1 = (v.y - mean) * rstd;
    float n2 = (v.z - mean) * rstd, n3 = (v.w - mean) * rstd;
    float4 r1;
    r1.x = n0 * G1.x + B1.x; r1.y = n1 * G1.y + B1.y;
    r1.z = n2 * G1.z + B1.z; r1.w = n3 * G1.w + B1.w;
    ((float4*)(o1 + (size_t)row * DM))[tid] = r1;
    ushort4 r2;
    r2.x = f2bf(n0 * G2.x + B2.x); r2.y = f2bf(n1 * G2.y + B2.y);
    r2.z = f2bf(n2 * G2.z + B2.z); r2.w = f2bf(n3 * G2.w + B2.w);
    ((ushort4*)(o2 + (size_t)row * DM))[tid] = r2;
}

__global__ __launch_bounds__(256) void ln_bf16_kernel(
    const float* __restrict__ x,
    const float* __restrict__ g1, const float* __restrict__ b1,
    u16* __restrict__ o1)
{
    __shared__ float sred[8];
    int row = blockIdx.x, tid = threadIdx.x;
    const float4 v = ((const float4*)(x + (size_t)row * DM))[tid];
    float s = v.x + v.y + v.z + v.w;
    float q = v.x * v.x + v.y * v.y + v.z * v.z + v.w * v.w;
#pragma unroll
    for (int o = 32; o > 0; o >>= 1) { s += __shfl_down(s, o); q += __shfl_down(q, o); }
    if ((tid & 63) == 0) { sred[(tid >> 6) * 2] = s; sred[(tid >> 6) * 2 + 1] = q; }
    __syncthreads();
    s = sred[0] + sred[2] + sred[4] + sred[6];
    q = sred[1] + sred[3] + sred[5] + sred[7];
    float mean = s * (1.f / DM);
    float var  = q * (1.f / DM) - mean * mean;
    float rstd = rsqrtf(var + 1e-5f);
    float4 G1 = ((const float4*)g1)[tid], B1 = ((const float4*)b1)[tid];
    ushort4 r1;
    r1.x = f2bf((v.x - mean) * rstd * G1.x + B1.x);
    r1.y = f2bf((v.y - mean) * rstd * G1.y + B1.y);
    r1.z = f2bf((v.z - mean) * rstd * G1.z + B1.z);
    r1.w = f2bf((v.w - mean) * rstd * G1.w + B1.w);
    ((ushort4*)(o1 + (size_t)row * DM))[tid] = r1;
}

// ---------------------------------------------------------------------------
// Group q/k projection (fp32, validated r2).
// ---------------------------------------------------------------------------
__global__ __launch_bounds__(512) void groupqk_kernel(
    const float* __restrict__ ctx,
    const float* __restrict__ wq, const float* __restrict__ bq,
    const float* __restrict__ wk, const float* __restrict__ bk,
    float* __restrict__ qg, float* __restrict__ kg)
{
    __shared__ float Wq[64][65], Wk[64][65], Ct[8][65];
    int tid = threadIdx.x;
    for (int t = tid; t < 4096; t += 512) {
        Wq[t >> 6][t & 63] = wq[t];
        Wk[t >> 6][t & 63] = wk[t];
    }
    int blk = blockIdx.x;
    int bh = blk >> 6;
    int i0 = (blk & 63) * 8;
    int b = bh >> 4, h = bh & 15;
    {
        int r = tid >> 6, c = tid & 63;
        Ct[r][c] = ctx[((size_t)b * S + i0 + r) * DM + h * 64 + c];
    }
    __syncthreads();
    int r = tid >> 6, j = tid & 63;
    float aq = bq[j], ak = bk[j];
#pragma unroll
    for (int d = 0; d < 64; ++d) {
        float c = Ct[r][d];
        aq = fmaf(c, Wq[d][j], aq);
        ak = fmaf(c, Wk[d][j], ak);
    }
    size_t o = ((size_t)bh * S + i0 + r) * DK + j;
    qg[o] = aq;
    kg[o] = ak;
}

// ---------------------------------------------------------------------------
// Adjacent scores -> 2-entry softmax -> na_adj -> prefix sums (fp32, r2).
// ---------------------------------------------------------------------------
__global__ __launch_bounds__(256) void adj_kernel(
    const float* __restrict__ qg, const float* __restrict__ kg,
    const int* __restrict__ eos, const float* __restrict__ prior,
    float* __restrict__ nap, float* __restrict__ Pout)
{
    __shared__ float su[S], sl[S], nu[S], nl[S], cl[S];
    int tid = threadIdx.x, bh = blockIdx.x, b = bh >> 4;
    const float* qb = qg + (size_t)bh * S * DK;
    const float* kb = kg + (size_t)bh * S * DK;
    for (int i = tid; i < S; i += 256) {
        float du = 0.f, dl = 0.f;
        const float* qi = qb + (size_t)i * DK;
        if (i < S - 1) {
            const float* kn = kb + (size_t)(i + 1) * DK;
            for (int d = 0; d < DK; ++d) du = fmaf(qi[d], kn[d], du);
        }
        if (i > 0) {
            const float* kp = kb + (size_t)(i - 1) * DK;
            for (int d = 0; d < DK; ++d) dl = fmaf(qi[d], kp[d], dl);
        }
        su[i] = du * (1.f / DK);
        sl[i] = dl * (1.f / DK);
    }
    __syncthreads();
    for (int i = tid; i < S; i += 256) {
        bool vu = (i < S - 1) && (eos[(size_t)b * S * S + (size_t)i * S + (i + 1)] != 0);
        bool vl = (i > 0)     && (eos[(size_t)b * S * S + (size_t)i * S + (i - 1)] != 0);
        float eu = 0.f, el = 0.f;
        if (vu && vl) {
            float m = fmaxf(su[i], sl[i]);
            eu = expf(su[i] - m);
            el = expf(sl[i] - m);
        } else if (vu) eu = 1.f;
        else if (vl) el = 1.f;
        float Z = eu + el;
        if (Z == 0.f) Z = 1.f;
        nu[i] = eu / Z;
        nl[i] = el / Z;
    }
    __syncthreads();
    float pr = prior[0];
    for (int i = tid; i < S - 1; i += 256) {
        float v = sqrtf(nu[i] * nl[i + 1] + 1e-4f);
        v = pr + (1.f - pr) * v;
        nap[(size_t)bh * S + i] = v;
        cl[i] = logf(v + 1e-9f);
    }
    if (tid == 0) cl[S - 1] = 0.f;
    __syncthreads();
    if (tid < 64) {
        float loc[8];
        float s8 = 0.f;
#pragma unroll
        for (int e = 0; e < 8; ++e) { loc[e] = cl[tid * 8 + e]; s8 += loc[e]; }
        float v = s8;
#pragma unroll
        for (int o = 1; o < 64; o <<= 1) {
            float n = __shfl_up(v, o);
            if (tid >= o) v += n;
        }
        float run = v - s8;
        float* Pb = Pout + (size_t)bh * S;
#pragma unroll
        for (int e = 0; e < 8; ++e) { Pb[tid * 8 + e] = run; run += loc[e]; }
    }
}

// ---------------------------------------------------------------------------
// na / group_prob output fills (fp32, r2).
// ---------------------------------------------------------------------------
__global__ void na_fill_kernel(const float* __restrict__ nap,
                               const float* __restrict__ prior,
                               float* __restrict__ out_na)
{
    float pr = prior[0];
    float base = pr + (1.f - pr) * 0.01f;
    size_t n4 = ATTSZ / 4;
    for (size_t t = (size_t)blockIdx.x * 256 + threadIdx.x; t < n4;
         t += (size_t)gridDim.x * 256) {
        size_t e = t * 4;
        int bh = (int)(e >> 18);
        int rem = (int)(e & 262143);
        int i = rem >> 9;
        int j0 = rem & 511;
        float4 v;
        float* vp = &v.x;
#pragma unroll
        for (int jj = 0; jj < 4; ++jj) {
            int j = j0 + jj;
            float val = base;
            if (j == i + 1)      val = nap[(size_t)bh * S + i];
            else if (j + 1 == i) val = nap[(size_t)bh * S + j];
            vp[jj] = val;
        }
        ((float4*)out_na)[t] = v;
    }
}

__global__ __launch_bounds__(256) void gp_fill_kernel(
    const float* __restrict__ Pin, const float* __restrict__ prior,
    float* __restrict__ out_gp)
{
    __shared__ float Pl[S];
    int bh = blockIdx.y;
    int i0 = blockIdx.x * 4;
    int tid = threadIdx.x;
    Pl[tid]       = Pin[(size_t)bh * S + tid];
    Pl[tid + 256] = Pin[(size_t)bh * S + tid + 256];
    __syncthreads();
    float pr = prior[0];
    float base = pr + (1.f - pr) * 0.01f;
    int r  = tid >> 6;
    int j0 = (tid & 63) * 8;
    int i  = i0 + r;
    float vals[8];
#pragma unroll
    for (int jj = 0; jj < 8; ++jj) {
        int j = j0 + jj;
        float val;
        if (i == j) {
            val = base;
        } else {
            int a = min(i, j), bb = max(i, j);
            float t1 = Pl[min(bb, S - 2) + 1] - Pl[max(a - 1, 0)];
            float t2 = Pl[min(bb - 1, S - 2) + 1] - Pl[a];
            val = expf(t1 + t2) + 1e-4f;
        }
        vals[jj] = val;
    }
    float* orow = out_gp + ((size_t)bh * S + i) * S + j0;
    *(float4*)&orow[0] = *(float4*)&vals[0];
    *(float4*)&orow[4] = *(float4*)&vals[4];
}

// ---------------------------------------------------------------------------
// Fused QKV projection GEMM: M=2048, N=3072 (q|k|v), K=1024.
// q2/k2 -> [bh][s][d] bf16; v -> v2T [bh][d][s] bf16 (for PV's B^T operand).
// ---------------------------------------------------------------------------
__global__ __launch_bounds__(256) void qkv_gemm(
    const u16* __restrict__ xn, const u16* __restrict__ wqkvT,
    const float* __restrict__ bq_, const float* __restrict__ bk_,
    const float* __restrict__ bv_,
    u16* __restrict__ q2, u16* __restrict__ k2, u16* __restrict__ v2T)
{
    __shared__ __align__(16) u16 As[128 * 32], Bs[128 * 32];
    int m0 = blockIdx.y * 128, n0 = blockIdx.x * 128;
    f32x4 acc[4][4] = {};
    mfma_loop<4>(xn + (size_t)m0 * DM, wqkvT + (size_t)n0 * DM, DM, DM, DM,
                 As, Bs, acc);
    int tid = threadIdx.x, lane = tid & 63, wv = tid >> 6;
    int wr = wv >> 1, wc = wv & 1;
    int region = n0 >> 10;
    const float* bias = region == 0 ? bq_ : (region == 1 ? bk_ : bv_);
    int b = m0 >> 9;
    if (region < 2) {
        u16* dst = region == 0 ? q2 : k2;
#pragma unroll
        for (int mi = 0; mi < 4; ++mi) {
#pragma unroll
            for (int nj = 0; nj < 4; ++nj) {
                int nn = (n0 + wc * 64 + nj * 16 + (lane & 15)) & 1023;
                int h = nn >> 6, d = nn & 63;
                float bv = bias[nn];
#pragma unroll
                for (int reg = 0; reg < 4; ++reg) {
                    int s = (m0 & 511) + wr * 64 + mi * 16 + (lane >> 4) * 4 + reg;
                    dst[((size_t)(b * H + h) * S + s) * DK + d] =
                        f2bf(acc[mi][nj][reg] + bv);
                }
            }
        }
    } else {
#pragma unroll
        for (int mi = 0; mi < 4; ++mi) {
            int s0 = (m0 & 511) + wr * 64 + mi * 16 + (lane >> 4) * 4;
#pragma unroll
            for (int nj = 0; nj < 4; ++nj) {
                int nn = (n0 + wc * 64 + nj * 16 + (lane & 15)) & 1023;
                int h = nn >> 6, d = nn & 63;
                float bv = bias[nn];
                ushort4 pk;
                pk.x = f2bf(acc[mi][nj][0] + bv);
                pk.y = f2bf(acc[mi][nj][1] + bv);
                pk.z = f2bf(acc[mi][nj][2] + bv);
                pk.w = f2bf(acc[mi][nj][3] + bv);
                *(ushort4*)&v2T[((size_t)(b * H + h) * DK + d) * S + s0] = pk;
            }
        }
    }
}

// ---------------------------------------------------------------------------
// FFN1: h1 = relu(xn2 @ W1 + b1), bf16 out. M=2048, N=4096, K=1024.
// ---------------------------------------------------------------------------
__global__ __launch_bounds__(256) void ffn1_gemm(
    const u16* __restrict__ xn2, const u16* __restrict__ w1T,
    const float* __restrict__ b1, u16* __restrict__ h1)
{
    __shared__ __align__(16) u16 As[128 * 32], Bs[128 * 32];
    int m0 = blockIdx.y * 128, n0 = blockIdx.x * 128;
    f32x4 acc[4][4] = {};
    mfma_loop<4>(xn2 + (size_t)m0 * DM, w1T + (size_t)n0 * DM, DM, DM, DM,
                 As, Bs, acc);
    int tid = threadIdx.x, lane = tid & 63, wv = tid >> 6;
    int wr = wv >> 1, wc = wv & 1;
#pragma unroll
    for (int mi = 0; mi < 4; ++mi) {
#pragma unroll
        for (int nj = 0; nj < 4; ++nj) {
            int n = n0 + wc * 64 + nj * 16 + (lane & 15);
            float bv = b1[n];
#pragma unroll
            for (int reg = 0; reg < 4; ++reg) {
                int m = m0 + wr * 64 + mi * 16 + (lane >> 4) * 4 + reg;
                h1[(size_t)m * FF + n] = f2bf(fmaxf(acc[mi][nj][reg] + bv, 0.f));
            }
        }
    }
}

// ---------------------------------------------------------------------------
// FFN2 + residual: out = h1 @ W2 + b2 + xmid. M=2048, N=1024, K=4096.
// BN=64 (NF=2) -> 256 blocks for co-residency on the deep-K loop.
// ---------------------------------------------------------------------------
__global__ __launch_bounds__(256) void ffn2_gemm(
    const u16* __restrict__ h1, const u16* __restrict__ w2T,
    const float* __restrict__ b2, const float* __restrict__ xmid,
    float* __restrict__ out_x)
{
    __shared__ __align__(16) u16 As[128 * 32], Bs[64 * 32];
    int m0 = blockIdx.y * 128, n0 = blockIdx.x * 64;
    f32x4 acc[4][2] = {};
    mfma_loop<2>(h1 + (size_t)m0 * FF, w2T + (size_t)n0 * FF, FF, FF, FF,
                 As, Bs, acc);
    int tid = threadIdx.x, lane = tid & 63, wv = tid >> 6;
    int wr = wv >> 1, wc = wv & 1;
#pragma unroll
    for (int mi = 0; mi < 4; ++mi) {
#pragma unroll
        for (int nj = 0; nj < 2; ++nj) {
            int n = n0 + wc * 32 + nj * 16 + (lane & 15);
            float bv = b2[n];
#pragma unroll
            for (int reg = 0; reg < 4; ++reg) {
                int m = m0 + wr * 64 + mi * 16 + (lane >> 4) * 4 + reg;
                size_t o = (size_t)m * DM + n;
                out_x[o] = acc[mi][nj][reg] + bv + xmid[o];
            }
        }
    }
}

// ---------------------------------------------------------------------------
// Attention scores: att = (q2 @ k2^T) / 8, bf16 out. Per bh: 512x512, K=64.
// ---------------------------------------------------------------------------
__global__ __launch_bounds__(256) void scores_gemm(
    const u16* __restrict__ q2, const u16* __restrict__ k2,
    u16* __restrict__ att)
{
    __shared__ __align__(16) u16 As[128 * 32], Bs[128 * 32];
    int bh = blockIdx.z;
    int m0 = blockIdx.y * 128, n0 = blockIdx.x * 128;
    f32x4 acc[4][4] = {};
    mfma_loop<4>(q2 + ((size_t)bh * S + m0) * DK,
                 k2 + ((size_t)bh * S + n0) * DK, DK, DK, DK, As, Bs, acc);
    int tid = threadIdx.x, lane = tid & 63, wv = tid >> 6;
    int wr = wv >> 1, wc = wv & 1;
    u16* C = att + (size_t)bh * S * S;
#pragma unroll
    for (int mi = 0; mi < 4; ++mi) {
#pragma unroll
        for (int nj = 0; nj < 4; ++nj) {
            int n = n0 + wc * 64 + nj * 16 + (lane & 15);
#pragma unroll
            for (int reg = 0; reg < 4; ++reg) {
                int m = m0 + wr * 64 + mi * 16 + (lane >> 4) * 4 + reg;
                C[(size_t)m * S + n] = f2bf(acc[mi][nj][reg] * 0.125f);
            }
        }
    }
}

// ---------------------------------------------------------------------------
// Row softmax x group_prob, in place on bf16 att. One block per (bh,row).
// ---------------------------------------------------------------------------
__global__ __launch_bounds__(256) void softmax_gp_kernel(
    u16* __restrict__ att, const float* __restrict__ gp)
{
    __shared__ float sred[4];
    size_t row = blockIdx.x;
    u16* ar = att + row * S;
    const float* gr = gp + row * S;
    int tid = threadIdx.x;
    ushort2 v = ((const ushort2*)ar)[tid];
    float a0 = bf2f(v.x), a1 = bf2f(v.y);
    float m = fmaxf(a0, a1);
#pragma unroll
    for (int o = 32; o > 0; o >>= 1) m = fmaxf(m, __shfl_down(m, o));
    if ((tid & 63) == 0) sred[tid >> 6] = m;
    __syncthreads();
    m = fmaxf(fmaxf(sred[0], sred[1]), fmaxf(sred[2], sred[3]));
    float e0 = expf(a0 - m), e1 = expf(a1 - m);
    float s = e0 + e1;
#pragma unroll
    for (int o = 32; o > 0; o >>= 1) s += __shfl_down(s, o);
    __syncthreads();
    if ((tid & 63) == 0) sred[tid >> 6] = s;
    __syncthreads();
    s = sred[0] + sred[1] + sred[2] + sred[3];
    float inv = 1.f / s;
    float2 g = ((const float2*)gr)[tid];
    ushort2 o2;
    o2.x = f2bf(e0 * inv * g.x);
    o2.y = f2bf(e1 * inv * g.y);
    ((ushort2*)ar)[tid] = o2;
}

// ---------------------------------------------------------------------------
// PV + residual: xmid = x + att @ v2. Per bh: M=512, N=64, K=512. NF=2.
// ---------------------------------------------------------------------------
__global__ __launch_bounds__(256) void pv_gemm(
    const u16* __restrict__ att, const u16* __restrict__ v2T,
    const float* __restrict__ x, float* __restrict__ xmid)
{
    __shared__ __align__(16) u16 As[128 * 32], Bs[64 * 32];
    int bh = blockIdx.z, b = bh >> 4, h = bh & 15;
    int m0 = blockIdx.y * 128;
    f32x4 acc[4][2] = {};
    mfma_loop<2>(att + ((size_t)bh * S + m0) * S,
                 v2T + (size_t)bh * DK * S, S, S, S, As, Bs, acc);
    int tid = threadIdx.x, lane = tid & 63, wv = tid >> 6;
    int wr = wv >> 1, wc = wv & 1;
#pragma unroll
    for (int mi = 0; mi < 4; ++mi) {
#pragma unroll
        for (int nj = 0; nj < 2; ++nj) {
            int d = wc * 32 + nj * 16 + (lane & 15);
#pragma unroll
            for (int reg = 0; reg < 4; ++reg) {
                int s = m0 + wr * 64 + mi * 16 + (lane >> 4) * 4 + reg;
                size_t o = ((size_t)b * S + s) * DM + h * 64 + d;
                xmid[o] = x[o] + acc[mi][nj][reg];
            }
        }
    }
}

// ---------------------------------------------------------------------------
extern "C" void kernel_launch(void* const* d_in, const int* in_sizes, int n_in,
                              void* d_out, int out_size, void* d_ws, size_t ws_size,
                              hipStream_t stream)
{
    const float* x     = (const float*)d_in[0];
    const int*   eos   = (const int*)d_in[1];
    const float* prior = (const float*)d_in[2];
    const float* gn_g  = (const float*)d_in[3];
    const float* gn_b  = (const float*)d_in[4];
    const float* wq    = (const float*)d_in[5];
    const float* bq    = (const float*)d_in[6];
    const float* wk    = (const float*)d_in[7];
    const float* bk    = (const float*)d_in[8];
    const float* fq_w  = (const float*)d_in[9];
    const float* fq_b  = (const float*)d_in[10];
    const float* fk_w  = (const float*)d_in[11];
    const float* fk_b  = (const float*)d_in[12];
    const float* fv_w  = (const float*)d_in[13];
    const float* fv_b  = (const float*)d_in[14];
    const float* ln1_g = (const float*)d_in[15];
    const float* ln1_b = (const float*)d_in[16];
    const float* ff_w1 = (const float*)d_in[17];
    const float* ff_b1 = (const float*)d_in[18];
    const float* ff_w2 = (const float*)d_in[19];
    const float* ff_b2 = (const float*)d_in[20];
    const float* ln2_g = (const float*)d_in[21];
    const float* ln2_b = (const float*)d_in[22];

    char* W = (char*)d_ws;
    // phase-aliased workspace (offsets in bytes); total 83 MB
    float* ctx   = (float*)(W + 0);                     // 8MB   (dead after groupqk)
    u16*   q2    = (u16*)(W + 0);                       // 4MB   alias
    u16*   k2    = (u16*)(W + ((size_t)4 << 20));       // 4MB   alias
    u16*   xn    = (u16*)(W + ((size_t)8 << 20));       // 4MB
    float* qg    = (float*)(W + ((size_t)12 << 20));    // 8MB   (dead after adj)
    float* xmid  = (float*)(W + ((size_t)12 << 20));    // alias
    float* kg    = (float*)(W + ((size_t)20 << 20));    // 8MB   (dead after adj)
    u16*   v2T   = (u16*)(W + ((size_t)20 << 20));      // 4MB   alias
    u16*   xn2   = (u16*)(W + ((size_t)24 << 20));      // 4MB   alias
    float* nap   = (float*)(W + ((size_t)28 << 20));    // 128KB
    float* Pp    = (float*)(W + ((size_t)28 << 20) + (128 << 10)); // 128KB
    u16*   att   = (u16*)(W + ((size_t)29 << 20));      // 32MB  (dead after pv)
    u16*   h1    = (u16*)(W + ((size_t)29 << 20));      // 16MB  alias
    u16*   wqkvT = (u16*)(W + ((size_t)61 << 20));      // 6MB
    u16*   w1T   = (u16*)(W + ((size_t)67 << 20));      // 8MB
    u16*   w2T   = (u16*)(W + ((size_t)75 << 20));      // 8MB

    float* out_x  = (float*)d_out;
    float* out_gp = out_x + XSZ;
    float* out_na = out_gp + ATTSZ;

    const int NTOK = BS * S;  // 2048

    // 0. weight transpose + convert to bf16
    transcvt<<<dim3(16, 16), 256, 0, stream>>>(fq_w, wqkvT, DM, DM);
    transcvt<<<dim3(16, 16), 256, 0, stream>>>(fk_w, wqkvT + (size_t)DM * DM, DM, DM);
    transcvt<<<dim3(16, 16), 256, 0, stream>>>(fv_w, wqkvT + 2 * (size_t)DM * DM, DM, DM);
    transcvt<<<dim3(16, 64), 256, 0, stream>>>(ff_w1, w1T, DM, FF);
    transcvt<<<dim3(64, 16), 256, 0, stream>>>(ff_w2, w2T, FF, DM);
    // 1. both pre-norms of x
    ln_dual_kernel<<<NTOK, 256, 0, stream>>>(x, gn_g, gn_b, ln1_g, ln1_b, ctx, xn);
    // 2. group q/k projection
    groupqk_kernel<<<BS * H * (S / 8), 512, 0, stream>>>(ctx, wq, bq, wk, bk, qg, kg);
    // 3. adjacent scores -> na_adj -> prefix sums
    adj_kernel<<<BS * H, 256, 0, stream>>>(qg, kg, eos, prior, nap, Pp);
    // 4/5. output fills
    na_fill_kernel<<<2048, 256, 0, stream>>>(nap, prior, out_na);
    gp_fill_kernel<<<dim3(S / 4, BS * H), 256, 0, stream>>>(Pp, prior, out_gp);
    // 6. fused QKV projection (MFMA)
    qkv_gemm<<<dim3(24, 16), 256, 0, stream>>>(xn, wqkvT, fq_b, fk_b, fv_b,
                                               q2, k2, v2T);
    // 7. attention scores (MFMA)
    scores_gemm<<<dim3(4, 4, BS * H), 256, 0, stream>>>(q2, k2, att);
    // 8. softmax * group_prob (in place, bf16)
    softmax_gp_kernel<<<BS * H * S, 256, 0, stream>>>(att, out_gp);
    // 9. PV + residual (MFMA)
    pv_gemm<<<dim3(1, 4, BS * H), 256, 0, stream>>>(att, v2T, x, xmid);
    // 10. LN2 -> bf16
    ln_bf16_kernel<<<NTOK, 256, 0, stream>>>(xmid, ln2_g, ln2_b, xn2);
    // 11. FFN1 (MFMA, relu)
    ffn1_gemm<<<dim3(32, 16), 256, 0, stream>>>(xn2, w1T, ff_b1, h1);
    // 12. FFN2 + residual (MFMA)
    ffn2_gemm<<<dim3(16, 16), 256, 0, stream>>>(h1, w2T, ff_b2, xmid, out_x);
}

// Round 8
// 463.210 us; speedup vs baseline: 3.5859x; 1.0157x over previous
//
#include <hip/hip_runtime.h>
#include <hip/hip_bf16.h>

// ---------------------------------------------------------------------------
// EncoderLayer with GroupAttention — r8: resubmit of r5/r6/r7 (never ran:
// infra failures). 2-phase prefetched MFMA GEMMs.
//
// vs r4 (470 us): double-buffered LDS + stage-next-before-compute (T3 minimal
// 2-phase, one barrier per K-step), wave-per-row softmax_gp, merged transcvt
// (5->1) and merged na/gp fill (2->1). Numerics unchanged.
// ---------------------------------------------------------------------------

#define BS   4
#define S    512
#define DM   1024
#define H    16
#define DK   64
#define FF   4096

typedef unsigned short u16;
typedef __attribute__((ext_vector_type(8))) short bf16x8;
typedef __attribute__((ext_vector_type(4))) float f32x4;

static constexpr size_t XSZ   = (size_t)BS * S * DM;      // 2,097,152
static constexpr size_t ATTSZ = (size_t)BS * H * S * S;   // 16,777,216

__device__ __forceinline__ u16 f2bf(float f) {
    union { float f; unsigned u; } v; v.f = f;
    unsigned u = v.u;
    return (u16)((u + 0x7FFFu + ((u >> 16) & 1u)) >> 16);
}
__device__ __forceinline__ float bf2f(u16 h) {
    union { unsigned u; float f; } v; v.u = ((unsigned)h) << 16;
    return v.f;
}

__device__ __forceinline__ void gload16(const void* g, void* lds) {
    __builtin_amdgcn_global_load_lds(
        (const __attribute__((address_space(1))) unsigned int*)g,
        (__attribute__((address_space(3))) unsigned int*)lds,
        16, 0, 0);
}

// ---------------------------------------------------------------------------
// MFMA GEMM core: block = 128 x (2*NF*16), 256 threads = 4 waves (2x2),
// wave tile 64 x (NF*16), BK=32, double-buffered LDS, prefetch 1 K-step.
// A [M][K] bf16, B^T [N][K] bf16. Requires K/32 even (all call sites: 32,
// 128, 2, 16).
// ---------------------------------------------------------------------------
template <int NF>
__device__ __forceinline__ void stage32(
    const u16* __restrict__ Ag, const u16* __restrict__ Bg,
    int lda, int ldb, int k0, u16* As, u16* Bs, int tid, int wv)
{
#pragma unroll
    for (int i = 0; i < 2; ++i) {
        int chunk = i * 256 + tid;
        int r = chunk >> 2, c = chunk & 3;
        gload16(Ag + (size_t)r * lda + k0 + c * 8, &As[(i * 256 + wv * 64) * 8]);
    }
    constexpr int BISS = (2 * NF * 16) / 64;    // 2 (NF=4) or 1 (NF=2)
#pragma unroll
    for (int i = 0; i < BISS; ++i) {
        int chunk = i * 256 + tid;
        int r = chunk >> 2, c = chunk & 3;
        gload16(Bg + (size_t)r * ldb + k0 + c * 8, &Bs[(i * 256 + wv * 64) * 8]);
    }
}

template <int NF>
__device__ __forceinline__ void compute32(
    const u16* As, const u16* Bs, f32x4 (&acc)[4][NF],
    int wr, int wc, int arow, int ak)
{
    bf16x8 af[4], bfr[NF];
#pragma unroll
    for (int mi = 0; mi < 4; ++mi)
        af[mi] = *(const bf16x8*)&As[(wr * 64 + mi * 16 + arow) * 32 + ak];
#pragma unroll
    for (int nj = 0; nj < NF; ++nj)
        bfr[nj] = *(const bf16x8*)&Bs[(wc * NF * 16 + nj * 16 + arow) * 32 + ak];
#pragma unroll
    for (int mi = 0; mi < 4; ++mi)
#pragma unroll
        for (int nj = 0; nj < NF; ++nj)
            acc[mi][nj] = __builtin_amdgcn_mfma_f32_16x16x32_bf16(
                af[mi], bfr[nj], acc[mi][nj], 0, 0, 0);
}

template <int NF>
__device__ __forceinline__ void mfma_loop(
    const u16* __restrict__ Ag, const u16* __restrict__ Bg,
    int lda, int ldb, int K,
    u16* As, u16* Bs,     // As[2][128*32], Bs[2][(2*NF*16)*32]
    f32x4 (&acc)[4][NF])
{
    const int tid  = threadIdx.x;
    const int lane = tid & 63;
    const int wv   = tid >> 6;
    const int wr   = wv >> 1, wc = wv & 1;
    const int arow = lane & 15;
    const int ak   = (lane >> 4) * 8;
    constexpr int BROWS = 2 * NF * 16;
    u16* As0 = As;             u16* As1 = As + 128 * 32;
    u16* Bs0 = Bs;             u16* Bs1 = Bs + BROWS * 32;
    const int nt = K >> 5;     // even at every call site

    stage32<NF>(Ag, Bg, lda, ldb, 0, As0, Bs0, tid, wv);
    __syncthreads();
    for (int t = 0; t < nt; t += 2) {
        // prefetch t+1 into buf1, compute buf0
        stage32<NF>(Ag, Bg, lda, ldb, (t + 1) << 5, As1, Bs1, tid, wv);
        compute32<NF>(As0, Bs0, acc, wr, wc, arow, ak);
        __syncthreads();
        // prefetch t+2 into buf0, compute buf1
        if (t + 2 < nt)
            stage32<NF>(Ag, Bg, lda, ldb, (t + 2) << 5, As0, Bs0, tid, wv);
        compute32<NF>(As1, Bs1, acc, wr, wc, arow, ak);
        __syncthreads();
    }
}

// ---------------------------------------------------------------------------
// Merged weight transpose + fp32->bf16 for all 5 weights (1 launch).
// src [K][N] fp32 -> dst [N][K] bf16, 64x64 tiles.
// ---------------------------------------------------------------------------
__global__ __launch_bounds__(256) void transcvt_all(
    const float* __restrict__ fq_w, const float* __restrict__ fk_w,
    const float* __restrict__ fv_w, const float* __restrict__ ff_w1,
    const float* __restrict__ ff_w2,
    u16* __restrict__ wqkvT, u16* __restrict__ w1T, u16* __restrict__ w2T)
{
    __shared__ __align__(16) u16 T[64][80];
    int blk = blockIdx.x, tid = threadIdx.x;
    const float* src; u16* dst; int K, N, kb, nb;
    if (blk < 768) {
        int w = blk >> 8, rem = blk & 255;
        src = w == 0 ? fq_w : (w == 1 ? fk_w : fv_w);
        dst = wqkvT + (size_t)w * DM * DM;
        K = DM; N = DM; kb = rem & 15; nb = rem >> 4;
    } else if (blk < 1792) {
        int rem = blk - 768;
        src = ff_w1; dst = w1T; K = DM; N = FF;
        kb = rem & 15; nb = rem >> 4;
    } else {
        int rem = blk - 1792;
        src = ff_w2; dst = w2T; K = FF; N = DM;
        kb = rem & 63; nb = rem >> 6;
    }
    int k0 = kb * 64, n0 = nb * 64;
    int r = tid >> 2, c0 = (tid & 3) * 16;
#pragma unroll
    for (int i = 0; i < 4; ++i) {
        float4 v = *(const float4*)&src[(size_t)(k0 + r) * N + n0 + c0 + i * 4];
        T[c0 + i * 4 + 0][r] = f2bf(v.x);
        T[c0 + i * 4 + 1][r] = f2bf(v.y);
        T[c0 + i * 4 + 2][r] = f2bf(v.z);
        T[c0 + i * 4 + 3][r] = f2bf(v.w);
    }
    __syncthreads();
    int n = tid >> 2, kc = (tid & 3) * 16;
#pragma unroll
    for (int i = 0; i < 2; ++i) {
        ushort4 a = *(const ushort4*)&T[n][kc + i * 8];
        ushort4 b = *(const ushort4*)&T[n][kc + i * 8 + 4];
        *(ushort4*)&dst[(size_t)(n0 + n) * K + k0 + kc + i * 8]     = a;
        *(ushort4*)&dst[(size_t)(n0 + n) * K + k0 + kc + i * 8 + 4] = b;
    }
}

// ---------------------------------------------------------------------------
// LN kernels. ln_dual: ctx fp32 (group path) + xn bf16 (QKV GEMM A-operand).
// ---------------------------------------------------------------------------
__global__ __launch_bounds__(256) void ln_dual_kernel(
    const float* __restrict__ x,
    const float* __restrict__ g1, const float* __restrict__ b1,
    const float* __restrict__ g2, const float* __restrict__ b2,
    float* __restrict__ o1, u16* __restrict__ o2)
{
    __shared__ float sred[8];
    int row = blockIdx.x, tid = threadIdx.x;
    const float4 v = ((const float4*)(x + (size_t)row * DM))[tid];
    float s = v.x + v.y + v.z + v.w;
    float q = v.x * v.x + v.y * v.y + v.z * v.z + v.w * v.w;
#pragma unroll
    for (int o = 32; o > 0; o >>= 1) { s += __shfl_down(s, o); q += __shfl_down(q, o); }
    if ((tid & 63) == 0) { sred[(tid >> 6) * 2] = s; sred[(tid >> 6) * 2 + 1] = q; }
    __syncthreads();
    s = sred[0] + sred[2] + sred[4] + sred[6];
    q = sred[1] + sred[3] + sred[5] + sred[7];
    float mean = s * (1.f / DM);
    float var  = q * (1.f / DM) - mean * mean;
    float rstd = rsqrtf(var + 1e-5f);
    float4 G1 = ((const float4*)g1)[tid], B1 = ((const float4*)b1)[tid];
    float4 G2 = ((const float4*)g2)[tid], B2 = ((const float4*)b2)[tid];
    float n0 = (v.x - mean) * rstd, n1 = (v.y - mean) * rstd;
    float n2 = (v.z - mean) * rstd, n3 = (v.w - mean) * rstd;
    float4 r1;
    r1.x = n0 * G1.x + B1.x; r1.y = n1 * G1.y + B1.y;
    r1.z = n2 * G1.z + B1.z; r1.w = n3 * G1.w + B1.w;
    ((float4*)(o1 + (size_t)row * DM))[tid] = r1;
    ushort4 r2;
    r2.x = f2bf(n0 * G2.x + B2.x); r2.y = f2bf(n1 * G2.y + B2.y);
    r2.z = f2bf(n2 * G2.z + B2.z); r2.w = f2bf(n3 * G2.w + B2.w);
    ((ushort4*)(o2 + (size_t)row * DM))[tid] = r2;
}

__global__ __launch_bounds__(256) void ln_bf16_kernel(
    const float* __restrict__ x,
    const float* __restrict__ g1, const float* __restrict__ b1,
    u16* __restrict__ o1)
{
    __shared__ float sred[8];
    int row = blockIdx.x, tid = threadIdx.x;
    const float4 v = ((const float4*)(x + (size_t)row * DM))[tid];
    float s = v.x + v.y + v.z + v.w;
    float q = v.x * v.x + v.y * v.y + v.z * v.z + v.w * v.w;
#pragma unroll
    for (int o = 32; o > 0; o >>= 1) { s += __shfl_down(s, o); q += __shfl_down(q, o); }
    if ((tid & 63) == 0) { sred[(tid >> 6) * 2] = s; sred[(tid >> 6) * 2 + 1] = q; }
    __syncthreads();
    s = sred[0] + sred[2] + sred[4] + sred[6];
    q = sred[1] + sred[3] + sred[5] + sred[7];
    float mean = s * (1.f / DM);
    float var  = q * (1.f / DM) - mean * mean;
    float rstd = rsqrtf(var + 1e-5f);
    float4 G1 = ((const float4*)g1)[tid], B1 = ((const float4*)b1)[tid];
    ushort4 r1;
    r1.x = f2bf((v.x - mean) * rstd * G1.x + B1.x);
    r1.y = f2bf((v.y - mean) * rstd * G1.y + B1.y);
    r1.z = f2bf((v.z - mean) * rstd * G1.z + B1.z);
    r1.w = f2bf((v.w - mean) * rstd * G1.w + B1.w);
    ((ushort4*)(o1 + (size_t)row * DM))[tid] = r1;
}

// ---------------------------------------------------------------------------
// Group q/k projection (fp32, validated r2).
// ---------------------------------------------------------------------------
__global__ __launch_bounds__(512) void groupqk_kernel(
    const float* __restrict__ ctx,
    const float* __restrict__ wq, const float* __restrict__ bq,
    const float* __restrict__ wk, const float* __restrict__ bk,
    float* __restrict__ qg, float* __restrict__ kg)
{
    __shared__ float Wq[64][65], Wk[64][65], Ct[8][65];
    int tid = threadIdx.x;
    for (int t = tid; t < 4096; t += 512) {
        Wq[t >> 6][t & 63] = wq[t];
        Wk[t >> 6][t & 63] = wk[t];
    }
    int blk = blockIdx.x;
    int bh = blk >> 6;
    int i0 = (blk & 63) * 8;
    int b = bh >> 4, h = bh & 15;
    {
        int r = tid >> 6, c = tid & 63;
        Ct[r][c] = ctx[((size_t)b * S + i0 + r) * DM + h * 64 + c];
    }
    __syncthreads();
    int r = tid >> 6, j = tid & 63;
    float aq = bq[j], ak = bk[j];
#pragma unroll
    for (int d = 0; d < 64; ++d) {
        float c = Ct[r][d];
        aq = fmaf(c, Wq[d][j], aq);
        ak = fmaf(c, Wk[d][j], ak);
    }
    size_t o = ((size_t)bh * S + i0 + r) * DK + j;
    qg[o] = aq;
    kg[o] = ak;
}

// ---------------------------------------------------------------------------
// Adjacent scores -> 2-entry softmax -> na_adj -> prefix sums (fp32, r2).
// ---------------------------------------------------------------------------
__global__ __launch_bounds__(256) void adj_kernel(
    const float* __restrict__ qg, const float* __restrict__ kg,
    const int* __restrict__ eos, const float* __restrict__ prior,
    float* __restrict__ nap, float* __restrict__ Pout)
{
    __shared__ float su[S], sl[S], nu[S], nl[S], cl[S];
    int tid = threadIdx.x, bh = blockIdx.x, b = bh >> 4;
    const float* qb = qg + (size_t)bh * S * DK;
    const float* kb = kg + (size_t)bh * S * DK;
    for (int i = tid; i < S; i += 256) {
        float du = 0.f, dl = 0.f;
        const float* qi = qb + (size_t)i * DK;
        if (i < S - 1) {
            const float* kn = kb + (size_t)(i + 1) * DK;
            for (int d = 0; d < DK; ++d) du = fmaf(qi[d], kn[d], du);
        }
        if (i > 0) {
            const float* kp = kb + (size_t)(i - 1) * DK;
            for (int d = 0; d < DK; ++d) dl = fmaf(qi[d], kp[d], dl);
        }
        su[i] = du * (1.f / DK);
        sl[i] = dl * (1.f / DK);
    }
    __syncthreads();
    for (int i = tid; i < S; i += 256) {
        bool vu = (i < S - 1) && (eos[(size_t)b * S * S + (size_t)i * S + (i + 1)] != 0);
        bool vl = (i > 0)     && (eos[(size_t)b * S * S + (size_t)i * S + (i - 1)] != 0);
        float eu = 0.f, el = 0.f;
        if (vu && vl) {
            float m = fmaxf(su[i], sl[i]);
            eu = expf(su[i] - m);
            el = expf(sl[i] - m);
        } else if (vu) eu = 1.f;
        else if (vl) el = 1.f;
        float Z = eu + el;
        if (Z == 0.f) Z = 1.f;
        nu[i] = eu / Z;
        nl[i] = el / Z;
    }
    __syncthreads();
    float pr = prior[0];
    for (int i = tid; i < S - 1; i += 256) {
        float v = sqrtf(nu[i] * nl[i + 1] + 1e-4f);
        v = pr + (1.f - pr) * v;
        nap[(size_t)bh * S + i] = v;
        cl[i] = logf(v + 1e-9f);
    }
    if (tid == 0) cl[S - 1] = 0.f;
    __syncthreads();
    if (tid < 64) {
        float loc[8];
        float s8 = 0.f;
#pragma unroll
        for (int e = 0; e < 8; ++e) { loc[e] = cl[tid * 8 + e]; s8 += loc[e]; }
        float v = s8;
#pragma unroll
        for (int o = 1; o < 64; o <<= 1) {
            float n = __shfl_up(v, o);
            if (tid >= o) v += n;
        }
        float run = v - s8;
        float* Pb = Pout + (size_t)bh * S;
#pragma unroll
        for (int e = 0; e < 8; ++e) { Pb[tid * 8 + e] = run; run += loc[e]; }
    }
}

// ---------------------------------------------------------------------------
// Merged group_prob + na output fill. grid = (S/4, BS*H); block = 4 rows.
// ---------------------------------------------------------------------------
__global__ __launch_bounds__(256) void fill_gp_na_kernel(
    const float* __restrict__ Pin, const float* __restrict__ nap,
    const float* __restrict__ prior,
    float* __restrict__ out_gp, float* __restrict__ out_na)
{
    __shared__ float Pl[S];
    int bh = blockIdx.y;
    int i0 = blockIdx.x * 4;
    int tid = threadIdx.x;
    Pl[tid]       = Pin[(size_t)bh * S + tid];
    Pl[tid + 256] = Pin[(size_t)bh * S + tid + 256];
    __syncthreads();
    float pr = prior[0];
    float base = pr + (1.f - pr) * 0.01f;
    int r  = tid >> 6;
    int j0 = (tid & 63) * 8;
    int i  = i0 + r;
    float na_i   = (i < S - 1) ? nap[(size_t)bh * S + i]     : base;
    float na_im1 = (i > 0)     ? nap[(size_t)bh * S + i - 1] : base;
    float vals[8], nvals[8];
#pragma unroll
    for (int jj = 0; jj < 8; ++jj) {
        int j = j0 + jj;
        float val;
        if (i == j) {
            val = base;
        } else {
            int a = min(i, j), bb = max(i, j);
            float t1 = Pl[min(bb, S - 2) + 1] - Pl[max(a - 1, 0)];
            float t2 = Pl[min(bb - 1, S - 2) + 1] - Pl[a];
            val = expf(t1 + t2) + 1e-4f;
        }
        vals[jj] = val;
        float nv = base;
        if (j == i + 1)      nv = na_i;
        else if (j + 1 == i) nv = na_im1;
        nvals[jj] = nv;
    }
    float* orow = out_gp + ((size_t)bh * S + i) * S + j0;
    *(float4*)&orow[0] = *(float4*)&vals[0];
    *(float4*)&orow[4] = *(float4*)&vals[4];
    float* nrow = out_na + ((size_t)bh * S + i) * S + j0;
    *(float4*)&nrow[0] = *(float4*)&nvals[0];
    *(float4*)&nrow[4] = *(float4*)&nvals[4];
}

// ---------------------------------------------------------------------------
// Fused QKV projection GEMM: M=2048, N=3072 (q|k|v), K=1024.
// q2/k2 -> [bh][s][d] bf16; v -> v2T [bh][d][s] bf16 (for PV's B^T operand).
// ---------------------------------------------------------------------------
__global__ __launch_bounds__(256) void qkv_gemm(
    const u16* __restrict__ xn, const u16* __restrict__ wqkvT,
    const float* __restrict__ bq_, const float* __restrict__ bk_,
    const float* __restrict__ bv_,
    u16* __restrict__ q2, u16* __restrict__ k2, u16* __restrict__ v2T)
{
    __shared__ __align__(16) u16 As[2 * 128 * 32], Bs[2 * 128 * 32];
    int m0 = blockIdx.y * 128, n0 = blockIdx.x * 128;
    f32x4 acc[4][4] = {};
    mfma_loop<4>(xn + (size_t)m0 * DM, wqkvT + (size_t)n0 * DM, DM, DM, DM,
                 As, Bs, acc);
    int tid = threadIdx.x, lane = tid & 63, wv = tid >> 6;
    int wr = wv >> 1, wc = wv & 1;
    int region = n0 >> 10;
    const float* bias = region == 0 ? bq_ : (region == 1 ? bk_ : bv_);
    int b = m0 >> 9;
    if (region < 2) {
        u16* dst = region == 0 ? q2 : k2;
#pragma unroll
        for (int mi = 0; mi < 4; ++mi) {
#pragma unroll
            for (int nj = 0; nj < 4; ++nj) {
                int nn = (n0 + wc * 64 + nj * 16 + (lane & 15)) & 1023;
                int h = nn >> 6, d = nn & 63;
                float bv = bias[nn];
#pragma unroll
                for (int reg = 0; reg < 4; ++reg) {
                    int s = (m0 & 511) + wr * 64 + mi * 16 + (lane >> 4) * 4 + reg;
                    dst[((size_t)(b * H + h) * S + s) * DK + d] =
                        f2bf(acc[mi][nj][reg] + bv);
                }
            }
        }
    } else {
#pragma unroll
        for (int mi = 0; mi < 4; ++mi) {
            int s0 = (m0 & 511) + wr * 64 + mi * 16 + (lane >> 4) * 4;
#pragma unroll
            for (int nj = 0; nj < 4; ++nj) {
                int nn = (n0 + wc * 64 + nj * 16 + (lane & 15)) & 1023;
                int h = nn >> 6, d = nn & 63;
                float bv = bias[nn];
                ushort4 pk;
                pk.x = f2bf(acc[mi][nj][0] + bv);
                pk.y = f2bf(acc[mi][nj][1] + bv);
                pk.z = f2bf(acc[mi][nj][2] + bv);
                pk.w = f2bf(acc[mi][nj][3] + bv);
                *(ushort4*)&v2T[((size_t)(b * H + h) * DK + d) * S + s0] = pk;
            }
        }
    }
}

// ---------------------------------------------------------------------------
// FFN1: h1 = relu(xn2 @ W1 + b1), bf16 out. M=2048, N=4096, K=1024.
// ---------------------------------------------------------------------------
__global__ __launch_bounds__(256) void ffn1_gemm(
    const u16* __restrict__ xn2, const u16* __restrict__ w1T,
    const float* __restrict__ b1, u16* __restrict__ h1)
{
    __shared__ __align__(16) u16 As[2 * 128 * 32], Bs[2 * 128 * 32];
    int m0 = blockIdx.y * 128, n0 = blockIdx.x * 128;
    f32x4 acc[4][4] = {};
    mfma_loop<4>(xn2 + (size_t)m0 * DM, w1T + (size_t)n0 * DM, DM, DM, DM,
                 As, Bs, acc);
    int tid = threadIdx.x, lane = tid & 63, wv = tid >> 6;
    int wr = wv >> 1, wc = wv & 1;
#pragma unroll
    for (int mi = 0; mi < 4; ++mi) {
#pragma unroll
        for (int nj = 0; nj < 4; ++nj) {
            int n = n0 + wc * 64 + nj * 16 + (lane & 15);
            float bv = b1[n];
#pragma unroll
            for (int reg = 0; reg < 4; ++reg) {
                int m = m0 + wr * 64 + mi * 16 + (lane >> 4) * 4 + reg;
                h1[(size_t)m * FF + n] = f2bf(fmaxf(acc[mi][nj][reg] + bv, 0.f));
            }
        }
    }
}

// ---------------------------------------------------------------------------
// FFN2 + residual: out = h1 @ W2 + b2 + xmid. M=2048, N=1024, K=4096.
// ---------------------------------------------------------------------------
__global__ __launch_bounds__(256) void ffn2_gemm(
    const u16* __restrict__ h1, const u16* __restrict__ w2T,
    const float* __restrict__ b2, const float* __restrict__ xmid,
    float* __restrict__ out_x)
{
    __shared__ __align__(16) u16 As[2 * 128 * 32], Bs[2 * 64 * 32];
    int m0 = blockIdx.y * 128, n0 = blockIdx.x * 64;
    f32x4 acc[4][2] = {};
    mfma_loop<2>(h1 + (size_t)m0 * FF, w2T + (size_t)n0 * FF, FF, FF, FF,
                 As, Bs, acc);
    int tid = threadIdx.x, lane = tid & 63, wv = tid >> 6;
    int wr = wv >> 1, wc = wv & 1;
#pragma unroll
    for (int mi = 0; mi < 4; ++mi) {
#pragma unroll
        for (int nj = 0; nj < 2; ++nj) {
            int n = n0 + wc * 32 + nj * 16 + (lane & 15);
            float bv = b2[n];
#pragma unroll
            for (int reg = 0; reg < 4; ++reg) {
                int m = m0 + wr * 64 + mi * 16 + (lane >> 4) * 4 + reg;
                size_t o = (size_t)m * DM + n;
                out_x[o] = acc[mi][nj][reg] + bv + xmid[o];
            }
        }
    }
}

// ---------------------------------------------------------------------------
// Attention scores: att = (q2 @ k2^T) / 8, bf16 out. Per bh: 512x512, K=64.
// ---------------------------------------------------------------------------
__global__ __launch_bounds__(256) void scores_gemm(
    const u16* __restrict__ q2, const u16* __restrict__ k2,
    u16* __restrict__ att)
{
    __shared__ __align__(16) u16 As[2 * 128 * 32], Bs[2 * 128 * 32];
    int bh = blockIdx.z;
    int m0 = blockIdx.y * 128, n0 = blockIdx.x * 128;
    f32x4 acc[4][4] = {};
    mfma_loop<4>(q2 + ((size_t)bh * S + m0) * DK,
                 k2 + ((size_t)bh * S + n0) * DK, DK, DK, DK, As, Bs, acc);
    int tid = threadIdx.x, lane = tid & 63, wv = tid >> 6;
    int wr = wv >> 1, wc = wv & 1;
    u16* C = att + (size_t)bh * S * S;
#pragma unroll
    for (int mi = 0; mi < 4; ++mi) {
#pragma unroll
        for (int nj = 0; nj < 4; ++nj) {
            int n = n0 + wc * 64 + nj * 16 + (lane & 15);
#pragma unroll
            for (int reg = 0; reg < 4; ++reg) {
                int m = m0 + wr * 64 + mi * 16 + (lane >> 4) * 4 + reg;
                C[(size_t)m * S + n] = f2bf(acc[mi][nj][reg] * 0.125f);
            }
        }
    }
}

// ---------------------------------------------------------------------------
// Row softmax x group_prob, in place on bf16 att. Wave-per-row; no max pass
// (softmax is shift-invariant; scores are O(1) here so exp is safe in fp32).
// grid = BS*H*S/4 blocks of 256 (4 waves).
// ---------------------------------------------------------------------------
__global__ __launch_bounds__(256) void softmax_gp_kernel(
    u16* __restrict__ att, const float* __restrict__ gp)
{
    size_t row = (size_t)blockIdx.x * 4 + (threadIdx.x >> 6);
    int lane = threadIdx.x & 63;
    u16* ar = att + row * S;
    const float* gr = gp + row * S;
    bf16x8 v = *(const bf16x8*)&ar[lane * 8];
    float e[8];
    float s = 0.f;
#pragma unroll
    for (int j = 0; j < 8; ++j) { e[j] = expf(bf2f((u16)v[j])); s += e[j]; }
#pragma unroll
    for (int o = 1; o < 64; o <<= 1) s += __shfl_xor(s, o);
    float inv = 1.f / s;
    float4 g0 = *(const float4*)&gr[lane * 8];
    float4 g1 = *(const float4*)&gr[lane * 8 + 4];
    bf16x8 o8;
    o8[0] = (short)f2bf(e[0] * inv * g0.x);
    o8[1] = (short)f2bf(e[1] * inv * g0.y);
    o8[2] = (short)f2bf(e[2] * inv * g0.z);
    o8[3] = (short)f2bf(e[3] * inv * g0.w);
    o8[4] = (short)f2bf(e[4] * inv * g1.x);
    o8[5] = (short)f2bf(e[5] * inv * g1.y);
    o8[6] = (short)f2bf(e[6] * inv * g1.z);
    o8[7] = (short)f2bf(e[7] * inv * g1.w);
    *(bf16x8*)&ar[lane * 8] = o8;
}

// ---------------------------------------------------------------------------
// PV + residual: xmid = x + att @ v2. Per bh: M=512, N=64, K=512. NF=2.
// ---------------------------------------------------------------------------
__global__ __launch_bounds__(256) void pv_gemm(
    const u16* __restrict__ att, const u16* __restrict__ v2T,
    const float* __restrict__ x, float* __restrict__ xmid)
{
    __shared__ __align__(16) u16 As[2 * 128 * 32], Bs[2 * 64 * 32];
    int bh = blockIdx.z, b = bh >> 4, h = bh & 15;
    int m0 = blockIdx.y * 128;
    f32x4 acc[4][2] = {};
    mfma_loop<2>(att + ((size_t)bh * S + m0) * S,
                 v2T + (size_t)bh * DK * S, S, S, S, As, Bs, acc);
    int tid = threadIdx.x, lane = tid & 63, wv = tid >> 6;
    int wr = wv >> 1, wc = wv & 1;
#pragma unroll
    for (int mi = 0; mi < 4; ++mi) {
#pragma unroll
        for (int nj = 0; nj < 2; ++nj) {
            int d = wc * 32 + nj * 16 + (lane & 15);
#pragma unroll
            for (int reg = 0; reg < 4; ++reg) {
                int s = m0 + wr * 64 + mi * 16 + (lane >> 4) * 4 + reg;
                size_t o = ((size_t)b * S + s) * DM + h * 64 + d;
                xmid[o] = x[o] + acc[mi][nj][reg];
            }
        }
    }
}

// ---------------------------------------------------------------------------
extern "C" void kernel_launch(void* const* d_in, const int* in_sizes, int n_in,
                              void* d_out, int out_size, void* d_ws, size_t ws_size,
                              hipStream_t stream)
{
    const float* x     = (const float*)d_in[0];
    const int*   eos   = (const int*)d_in[1];
    const float* prior = (const float*)d_in[2];
    const float* gn_g  = (const float*)d_in[3];
    const float* gn_b  = (const float*)d_in[4];
    const float* wq    = (const float*)d_in[5];
    const float* bq    = (const float*)d_in[6];
    const float* wk    = (const float*)d_in[7];
    const float* bk    = (const float*)d_in[8];
    const float* fq_w  = (const float*)d_in[9];
    const float* fq_b  = (const float*)d_in[10];
    const float* fk_w  = (const float*)d_in[11];
    const float* fk_b  = (const float*)d_in[12];
    const float* fv_w  = (const float*)d_in[13];
    const float* fv_b  = (const float*)d_in[14];
    const float* ln1_g = (const float*)d_in[15];
    const float* ln1_b = (const float*)d_in[16];
    const float* ff_w1 = (const float*)d_in[17];
    const float* ff_b1 = (const float*)d_in[18];
    const float* ff_w2 = (const float*)d_in[19];
    const float* ff_b2 = (const float*)d_in[20];
    const float* ln2_g = (const float*)d_in[21];
    const float* ln2_b = (const float*)d_in[22];

    char* W = (char*)d_ws;
    // phase-aliased workspace (offsets in bytes); total 83 MB
    float* ctx   = (float*)(W + 0);                     // 8MB   (dead after groupqk)
    u16*   q2    = (u16*)(W + 0);                       // 4MB   alias
    u16*   k2    = (u16*)(W + ((size_t)4 << 20));       // 4MB   alias
    u16*   xn    = (u16*)(W + ((size_t)8 << 20));       // 4MB
    float* qg    = (float*)(W + ((size_t)12 << 20));    // 8MB   (dead after adj)
    float* xmid  = (float*)(W + ((size_t)12 << 20));    // alias
    float* kg    = (float*)(W + ((size_t)20 << 20));    // 8MB   (dead after adj)
    u16*   v2T   = (u16*)(W + ((size_t)20 << 20));      // 4MB   alias
    u16*   xn2   = (u16*)(W + ((size_t)24 << 20));      // 4MB   alias
    float* nap   = (float*)(W + ((size_t)28 << 20));    // 128KB
    float* Pp    = (float*)(W + ((size_t)28 << 20) + (128 << 10)); // 128KB
    u16*   att   = (u16*)(W + ((size_t)29 << 20));      // 32MB  (dead after pv)
    u16*   h1    = (u16*)(W + ((size_t)29 << 20));      // 16MB  alias
    u16*   wqkvT = (u16*)(W + ((size_t)61 << 20));      // 6MB
    u16*   w1T   = (u16*)(W + ((size_t)67 << 20));      // 8MB
    u16*   w2T   = (u16*)(W + ((size_t)75 << 20));      // 8MB

    float* out_x  = (float*)d_out;
    float* out_gp = out_x + XSZ;
    float* out_na = out_gp + ATTSZ;

    const int NTOK = BS * S;  // 2048

    // 0. all weight transposes + fp32->bf16 (one launch)
    transcvt_all<<<2816, 256, 0, stream>>>(fq_w, fk_w, fv_w, ff_w1, ff_w2,
                                           wqkvT, w1T, w2T);
    // 1. both pre-norms of x
    ln_dual_kernel<<<NTOK, 256, 0, stream>>>(x, gn_g, gn_b, ln1_g, ln1_b, ctx, xn);
    // 2. group q/k projection
    groupqk_kernel<<<BS * H * (S / 8), 512, 0, stream>>>(ctx, wq, bq, wk, bk, qg, kg);
    // 3. adjacent scores -> na_adj -> prefix sums
    adj_kernel<<<BS * H, 256, 0, stream>>>(qg, kg, eos, prior, nap, Pp);
    // 4. group_prob + na output fills (one launch)
    fill_gp_na_kernel<<<dim3(S / 4, BS * H), 256, 0, stream>>>(
        Pp, nap, prior, out_gp, out_na);
    // 5. fused QKV projection (MFMA, prefetched)
    qkv_gemm<<<dim3(24, 16), 256, 0, stream>>>(xn, wqkvT, fq_b, fk_b, fv_b,
                                               q2, k2, v2T);
    // 6. attention scores (MFMA)
    scores_gemm<<<dim3(4, 4, BS * H), 256, 0, stream>>>(q2, k2, att);
    // 7. softmax * group_prob (in place, wave-per-row)
    softmax_gp_kernel<<<BS * H * S / 4, 256, 0, stream>>>(att, out_gp);
    // 8. PV + residual (MFMA)
    pv_gemm<<<dim3(1, 4, BS * H), 256, 0, stream>>>(att, v2T, x, xmid);
    // 9. LN2 -> bf16
    ln_bf16_kernel<<<NTOK, 256, 0, stream>>>(xmid, ln2_g, ln2_b, xn2);
    // 10. FFN1 (MFMA, relu)
    ffn1_gemm<<<dim3(32, 16), 256, 0, stream>>>(xn2, w1T, ff_b1, h1);
    // 11. FFN2 + residual (MFMA)
    ffn2_gemm<<<dim3(16, 16), 256, 0, stream>>>(h1, w2T, ff_b2, xmid, out_x);
}